// Round 1
// baseline (6998.409 us; speedup 1.0000x reference)
//
#include <hip/hip_runtime.h>
#include <math.h>

#define NB 1000
#define NT 100
#define NI 264
#define NH 100
#define NO 264
#define NG 400          // 4*NH
#define KE 364          // NI + NH
#define XH_STRIDE 368   // padded LDS row stride (16B-aligned, stride%32=16 -> only 2-way (free) conflicts)

__device__ __forceinline__ float sigm(float x){
    return 1.f / (1.f + __expf(-x));
}
__device__ __forceinline__ float tanh_fast(float x){
    // 2/(1+e^-2x) - 1 : safe at both extremes (e->inf gives -1, e->0 gives +1)
    float e = __expf(-2.f * x);
    return 2.f / (1.f + e) - 1.f;
}

// ---------------- prep kernels ----------------

// Pack Wcat[n][k] = k<NI ? Wih[n][k] : Whh[n][k-NI]; bcat = bih+bhh
__global__ void prep_pack_enc(const float* __restrict__ Wih, const float* __restrict__ Whh,
                              const float* __restrict__ bih, const float* __restrict__ bhh,
                              float* __restrict__ Wcat, float* __restrict__ bcat)
{
    int idx = blockIdx.x * 256 + threadIdx.x;
    if (idx < NG * KE){
        int n = idx / KE, k = idx - n * KE;
        Wcat[idx] = (k < NI) ? Wih[n * NI + k] : Whh[n * NH + (k - NI)];
    }
    if (idx < NG) bcat[idx] = bih[idx] + bhh[idx];
}

// Wdec[n][k] = Whh[n][k] + sum_o Wih[n][o] * fcW[o][k]   (decoder feedback folded in)
__global__ void prep_wdec(const float* __restrict__ Wih, const float* __restrict__ Whh,
                          const float* __restrict__ fcW, float* __restrict__ Wdec)
{
    int idx = blockIdx.x * 256 + threadIdx.x;
    if (idx >= NG * NH) return;
    int n = idx / NH, k = idx - n * NH;
    float acc = Whh[idx];
    const float* wr = Wih + (size_t)n * NI;
    for (int o = 0; o < NI; ++o) acc = fmaf(wr[o], fcW[o * NH + k], acc);
    Wdec[idx] = acc;
}

// b0 = bih+bhh ; bdec = b0 + Wih @ fcb ; also zero the two loss accumulators
__global__ void prep_bias(const float* __restrict__ pb1, const float* __restrict__ pb2,
                          const float* __restrict__ pW,  const float* __restrict__ pfb,
                          const float* __restrict__ rb1, const float* __restrict__ rb2,
                          const float* __restrict__ rW,  const float* __restrict__ rfb,
                          float* __restrict__ b0_p, float* __restrict__ bdec_p,
                          float* __restrict__ b0_r, float* __restrict__ bdec_r,
                          float* __restrict__ loss)
{
    int tid = blockIdx.x * 256 + threadIdx.x;
    if (tid < 2) loss[tid] = 0.f;
    if (tid >= 2 * NG) return;
    int dd = tid / NG, n = tid - dd * NG;
    const float* b1 = dd ? rb1 : pb1;
    const float* b2 = dd ? rb2 : pb2;
    const float* W  = dd ? rW  : pW;
    const float* fb = dd ? rfb : pfb;
    float base = b1[n] + b2[n];
    float acc = base;
    const float* wr = W + (size_t)n * NI;
    for (int o = 0; o < NI; ++o) acc = fmaf(wr[o], fb[o], acc);
    if (dd){ b0_r[n] = base; bdec_r[n] = acc; }
    else   { b0_p[n] = base; bdec_p[n] = acc; }
}

// ---------------- encoder: persistent, 4 rows/block, thread=(m,j) owns 4 gates ----------------

__global__ __launch_bounds__(512) void encoder_kernel(
    const float* __restrict__ src, const float* __restrict__ Wcat,
    const float* __restrict__ bcat, float* __restrict__ h_out, float* __restrict__ c_out)
{
    __shared__ float sh_xh[4][XH_STRIDE];   // [row][0..263]=x_t, [264..363]=h
    const int tid = threadIdx.x;
    const int m0  = blockIdx.x << 2;
    const int m   = tid & 3;
    const int j   = tid >> 2;
    const bool act = (tid < 4 * NH);
    const int jj = act ? j : 0;

    float c_reg = 0.f, h_new = 0.f;
    float bi = 0.f, bf = 0.f, bg = 0.f, bo = 0.f;
    if (act){
        sh_xh[m][NI + j] = 0.f;     // h0 = 0
        bi = bcat[jj]; bf = bcat[NH + jj]; bg = bcat[2*NH + jj]; bo = bcat[3*NH + jj];
    }
    const float4* Wi = (const float4*)(Wcat + (size_t)jj * KE);
    const float4* Wf = (const float4*)(Wcat + (size_t)(NH   + jj) * KE);
    const float4* Wg = (const float4*)(Wcat + (size_t)(2*NH + jj) * KE);
    const float4* Wo = (const float4*)(Wcat + (size_t)(3*NH + jj) * KE);
    const float* srow0 = src + (size_t)m0 * NT * NI;

    for (int t = 0; t < NT; ++t){
        // stage x_t for the 4 rows (coalesced)
        for (int i = tid; i < 4 * NI; i += 512){
            int r = i / NI, col = i - r * NI;
            sh_xh[r][col] = srow0[(size_t)r * NT * NI + t * NI + col];
        }
        __syncthreads();    // x visible; also separates prev-step h write from reads
        if (act){
            float ai = bi, af = bf, ag = bg, ao = bo;
            const float4* xr = (const float4*)sh_xh[m];
            for (int q = 0; q < KE / 4; ++q){
                float4 x4 = xr[q];
                float4 wa = Wi[q], wb = Wf[q], wc = Wg[q], wd = Wo[q];
                ai += x4.x*wa.x + x4.y*wa.y + x4.z*wa.z + x4.w*wa.w;
                af += x4.x*wb.x + x4.y*wb.y + x4.z*wb.z + x4.w*wb.w;
                ag += x4.x*wc.x + x4.y*wc.y + x4.z*wc.z + x4.w*wc.w;
                ao += x4.x*wd.x + x4.y*wd.y + x4.z*wd.z + x4.w*wd.w;
            }
            float ii = sigm(ai), ff = sigm(af);
            float gg = tanh_fast(ag), oo = sigm(ao);
            c_reg = ff * c_reg + ii * gg;
            h_new = oo * tanh_fast(c_reg);
        }
        __syncthreads();    // all reads of old h done
        if (act) sh_xh[m][NI + j] = h_new;
        // next iteration's first sync separates this write from next reads
    }
    if (act){
        h_out[(size_t)(m0 + m) * NH + j] = h_new;
        c_out[(size_t)(m0 + m) * NH + j] = c_reg;
    }
}

// ---------------- decoder: 500 blocks (0..249 predict, 250..499 reconstruct) ----------------

__global__ __launch_bounds__(512) void decoder_kernel(
    const float* __restrict__ h_enc, const float* __restrict__ c_enc,
    const float* __restrict__ Whh_p, const float* __restrict__ Wdec_p,
    const float* __restrict__ b0_p,  const float* __restrict__ bdec_p,
    const float* __restrict__ fcW_p, const float* __restrict__ fcb_p,
    const float* __restrict__ trg,
    const float* __restrict__ Whh_r, const float* __restrict__ Wdec_r,
    const float* __restrict__ b0_r,  const float* __restrict__ bdec_r,
    const float* __restrict__ fcW_r, const float* __restrict__ fcb_r,
    const float* __restrict__ src,
    float* __restrict__ loss)
{
    __shared__ float sh_h[4][NH];
    __shared__ float sh_red[8];
    const int tid = threadIdx.x;
    const int d   = (blockIdx.x >= 250) ? 1 : 0;
    const int m0  = (blockIdx.x - d * 250) << 2;
    const float* Whh  = d ? Whh_r  : Whh_p;
    const float* Wdec = d ? Wdec_r : Wdec_p;
    const float* b0   = d ? b0_r   : b0_p;
    const float* bdec = d ? bdec_r : bdec_p;
    const float* fcW  = d ? fcW_r  : fcW_p;
    const float* fcb  = d ? fcb_r  : fcb_p;
    const float* tgt  = d ? src    : trg;

    const int m = tid & 3, j = tid >> 2;
    const bool act = (tid < 4 * NH);
    const int jj = act ? j : 0;
    float c_reg = 0.f, h_new = 0.f;
    if (act){
        c_reg    = c_enc[(size_t)(m0 + m) * NH + j];
        sh_h[m][j] = h_enc[(size_t)(m0 + m) * NH + j];
    }
    float loss_acc = 0.f;
    __syncthreads();

    for (int t = 0; t < NT; ++t){
        const float* W  = t ? Wdec : Whh;   // step 0: x=0 -> plain Whh; t>=1: folded weight
        const float* bb = t ? bdec : b0;
        if (act){
            float ai = bb[jj], af = bb[NH + jj], ag = bb[2*NH + jj], ao = bb[3*NH + jj];
            const float4* hr = (const float4*)sh_h[m];
            const float4* Wi = (const float4*)(W + (size_t)jj * NH);
            const float4* Wf = (const float4*)(W + (size_t)(NH   + jj) * NH);
            const float4* Wg = (const float4*)(W + (size_t)(2*NH + jj) * NH);
            const float4* Wo = (const float4*)(W + (size_t)(3*NH + jj) * NH);
            for (int q = 0; q < NH / 4; ++q){
                float4 h4 = hr[q];
                float4 wa = Wi[q], wb = Wf[q], wc = Wg[q], wd = Wo[q];
                ai += h4.x*wa.x + h4.y*wa.y + h4.z*wa.z + h4.w*wa.w;
                af += h4.x*wb.x + h4.y*wb.y + h4.z*wb.z + h4.w*wb.w;
                ag += h4.x*wc.x + h4.y*wc.y + h4.z*wc.z + h4.w*wc.w;
                ao += h4.x*wd.x + h4.y*wd.y + h4.z*wd.z + h4.w*wd.w;
            }
            float ii = sigm(ai), ff = sigm(af), gg = tanh_fast(ag), oo = sigm(ao);
            c_reg = ff * c_reg + ii * gg;
            h_new = oo * tanh_fast(c_reg);
        }
        __syncthreads();
        if (act) sh_h[m][j] = h_new;
        __syncthreads();

        // fused pred + squared error: pairs (mm, o), pred = h_new @ fcW^T + fcb
        const int ti = d ? (NT - 1 - t) : t;
        for (int p = tid; p < 4 * NO; p += 512){
            int mm = p / NO, o = p - mm * NO;
            float acc = fcb[o];
            const float4* hr2 = (const float4*)sh_h[mm];
            const float4* wr  = (const float4*)(fcW + (size_t)o * NH);
            for (int q = 0; q < NH / 4; ++q){
                float4 h4 = hr2[q]; float4 w4 = wr[q];
                acc += h4.x*w4.x + h4.y*w4.y + h4.z*w4.z + h4.w*w4.w;
            }
            float tv = tgt[(size_t)(m0 + mm) * NT * NI + (size_t)ti * NI + o];
            float df = acc - tv;
            loss_acc += df * df;
        }
        // no sync needed: next phase only reads sh_h, next write is after a sync
    }

    // block loss reduction -> one atomic per block
    for (int off = 32; off > 0; off >>= 1) loss_acc += __shfl_down(loss_acc, off);
    if ((tid & 63) == 0) sh_red[tid >> 6] = loss_acc;
    __syncthreads();
    if (tid == 0){
        float s = 0.f;
        for (int w = 0; w < 8; ++w) s += sh_red[w];
        atomicAdd(&loss[d], s);
    }
}

__global__ void finalize_kernel(const float* __restrict__ loss, float* __restrict__ out){
    if (threadIdx.x == 0){
        const float inv = 1.f / 26400000.f;   // B*T*O
        out[0] = loss[1] * inv;   // reconstruct_loss
        out[1] = loss[0] * inv;   // predict_loss
    }
}

extern "C" void kernel_launch(void* const* d_in, const int* in_sizes, int n_in,
                              void* d_out, int out_size, void* d_ws, size_t ws_size,
                              hipStream_t stream)
{
    const float* src  = (const float*)d_in[0];
    const float* trg  = (const float*)d_in[1];
    const float* eWih = (const float*)d_in[2];
    const float* eWhh = (const float*)d_in[3];
    const float* ebih = (const float*)d_in[4];
    const float* ebhh = (const float*)d_in[5];
    const float* pWih = (const float*)d_in[6];
    const float* pWhh = (const float*)d_in[7];
    const float* pbih = (const float*)d_in[8];
    const float* pbhh = (const float*)d_in[9];
    const float* pfcW = (const float*)d_in[10];
    const float* pfcb = (const float*)d_in[11];
    const float* rWih = (const float*)d_in[12];
    const float* rWhh = (const float*)d_in[13];
    const float* rbih = (const float*)d_in[14];
    const float* rbhh = (const float*)d_in[15];
    const float* rfcW = (const float*)d_in[16];
    const float* rfcb = (const float*)d_in[17];

    float* w      = (float*)d_ws;           // total use: 427,602 floats (~1.7 MB)
    float* Wcat   = w;                      // 145600
    float* bcat   = w + 145600;             // 400
    float* Wdec_p = w + 146000;             // 40000
    float* Wdec_r = w + 186000;             // 40000
    float* b0_p   = w + 226000;             // 400
    float* bdec_p = w + 226400;             // 400
    float* b0_r   = w + 226800;             // 400
    float* bdec_r = w + 227200;             // 400
    float* h_enc  = w + 227600;             // 100000
    float* c_enc  = w + 327600;             // 100000
    float* loss   = w + 427600;             // 2

    prep_pack_enc<<<(NG * KE + 255) / 256, 256, 0, stream>>>(eWih, eWhh, ebih, ebhh, Wcat, bcat);
    prep_wdec<<<(NG * NH + 255) / 256, 256, 0, stream>>>(pWih, pWhh, pfcW, Wdec_p);
    prep_wdec<<<(NG * NH + 255) / 256, 256, 0, stream>>>(rWih, rWhh, rfcW, Wdec_r);
    prep_bias<<<4, 256, 0, stream>>>(pbih, pbhh, pWih, pfcb, rbih, rbhh, rWih, rfcb,
                                     b0_p, bdec_p, b0_r, bdec_r, loss);
    encoder_kernel<<<250, 512, 0, stream>>>(src, Wcat, bcat, h_enc, c_enc);
    decoder_kernel<<<500, 512, 0, stream>>>(h_enc, c_enc,
        pWhh, Wdec_p, b0_p, bdec_p, pfcW, pfcb, trg,
        rWhh, Wdec_r, b0_r, bdec_r, rfcW, rfcb, src,
        loss);
    finalize_kernel<<<1, 64, 0, stream>>>(loss, (float*)d_out);
}

// Round 2
// 5768.863 us; speedup vs baseline: 1.2131x; 1.2131x over previous
//
#include <hip/hip_runtime.h>
#include <math.h>

#define NB 1000
#define NT 100
#define NI 264
#define NH 100
#define NO 264
#define NG 400          // 4*NH
#define EM 4            // encoder rows per block (250 blocks)
#define DM 8            // decoder rows per block (125 blocks per decoder)
#define FC_BASE 248     // threads [248,512) own fcW rows 0..263

__device__ __forceinline__ float sigm(float x){ return 1.f / (1.f + __expf(-x)); }
__device__ __forceinline__ float tanh_fast(float x){
    float e = __expf(-2.f * x);
    return 2.f / (1.f + e) - 1.f;
}

// ---------------- prep kernels ----------------

// WihT[k*400+n] = Wih[n*264+k]  (coalesced-write transpose); bcat = bih+bhh
__global__ void prep_enc(const float* __restrict__ Wih,
                         const float* __restrict__ bih, const float* __restrict__ bhh,
                         float* __restrict__ WihT, float* __restrict__ bcat)
{
    int idx = blockIdx.x * 256 + threadIdx.x;
    if (idx < NG * NI){
        int n = idx % NG, k = idx / NG;
        WihT[idx] = Wih[n * NI + k];
    }
    if (idx < NG) bcat[idx] = bih[idx] + bhh[idx];
}

// Wdec[n][k] = Whh[n][k] + sum_o Wih[n][o] * fcW[o][k]   (decoder feedback folded in)
__global__ void prep_wdec(const float* __restrict__ Wih, const float* __restrict__ Whh,
                          const float* __restrict__ fcW, float* __restrict__ Wdec)
{
    int idx = blockIdx.x * 256 + threadIdx.x;
    if (idx >= NG * NH) return;
    int n = idx / NH, k = idx - n * NH;
    float acc = Whh[idx];
    const float* wr = Wih + (size_t)n * NI;
    for (int o = 0; o < NI; ++o) acc = fmaf(wr[o], fcW[o * NH + k], acc);
    Wdec[idx] = acc;
}

// b0 = bih+bhh ; bdec = b0 + Wih @ fcb ; zero the two loss accumulators
__global__ void prep_bias(const float* __restrict__ pb1, const float* __restrict__ pb2,
                          const float* __restrict__ pW,  const float* __restrict__ pfb,
                          const float* __restrict__ rb1, const float* __restrict__ rb2,
                          const float* __restrict__ rW,  const float* __restrict__ rfb,
                          float* __restrict__ b0_p, float* __restrict__ bdec_p,
                          float* __restrict__ b0_r, float* __restrict__ bdec_r,
                          float* __restrict__ loss)
{
    int tid = blockIdx.x * 256 + threadIdx.x;
    if (tid < 2) loss[tid] = 0.f;
    if (tid >= 2 * NG) return;
    int dd = tid / NG, n = tid - dd * NG;
    const float* b1 = dd ? rb1 : pb1;
    const float* b2 = dd ? rb2 : pb2;
    const float* W  = dd ? rW  : pW;
    const float* fb = dd ? rfb : pfb;
    float base = b1[n] + b2[n];
    float acc = base;
    const float* wr = W + (size_t)n * NI;
    for (int o = 0; o < NI; ++o) acc = fmaf(wr[o], fb[o], acc);
    if (dd){ b0_r[n] = base; bdec_r[n] = acc; }
    else   { b0_p[n] = base; bdec_p[n] = acc; }
}

// ---------------- encoder: weight-stationary Whh, streamed WihT, 4 rows/block ----------------

__global__ __launch_bounds__(512, 2) void encoder_kernel(
    const float* __restrict__ src, const float* __restrict__ WihT,
    const float* __restrict__ Whh, const float* __restrict__ bcat,
    float* __restrict__ h_out, float* __restrict__ c_out)
{
    __shared__ float sh_x[EM][NI];        // current x_t for the 4 rows
    __shared__ float sh_h[EM][104];       // h (padded row stride, 16B aligned)
    __shared__ float sh_g[NG][EM + 1];    // gates, stride 5 breaks bank conflicts
    const int tid = threadIdx.x;
    const int m0  = blockIdx.x * EM;
    const bool act = tid < NG;
    const int n  = act ? tid : 0;
    const int mc = act ? tid / NH : 0;    // combine pair (mc, jc)
    const int jc = act ? tid % NH : 0;

    float4 wh[25];                        // Whh row n, register-resident
    float bias = 0.f;
    if (act){
        const float4* whp = (const float4*)(Whh + (size_t)n * NH);
        #pragma unroll
        for (int q = 0; q < 25; ++q) wh[q] = whp[q];
        bias = bcat[n];
        sh_h[mc][jc] = 0.f;               // h0 = 0
    }
    float c_reg = 0.f, h_new = 0.f;
    const float* s0 = src + (size_t)m0 * NT * NI;

    for (int t = 0; t < NT; ++t){
        // stage x_t (coalesced)
        for (int i = tid; i < EM * NI; i += 512){
            int r = i / NI, k = i - r * NI;
            sh_x[r][k] = s0[(size_t)r * NT * NI + t * NI + k];
        }
        __syncthreads();
        if (act){
            float a0 = bias, a1 = bias, a2 = bias, a3 = bias;
            const float4* x0 = (const float4*)sh_x[0];
            const float4* x1 = (const float4*)sh_x[1];
            const float4* x2 = (const float4*)sh_x[2];
            const float4* x3 = (const float4*)sh_x[3];
            // x-projection: WihT streamed from L2 (coalesced), x broadcast from LDS
            #pragma unroll 4
            for (int k4 = 0; k4 < NI / 4; ++k4){
                int kb = k4 * 4;
                float w0 = WihT[(kb + 0) * NG + n];
                float w1 = WihT[(kb + 1) * NG + n];
                float w2 = WihT[(kb + 2) * NG + n];
                float w3 = WihT[(kb + 3) * NG + n];
                float4 xa = x0[k4]; a0 += xa.x*w0 + xa.y*w1 + xa.z*w2 + xa.w*w3;
                float4 xb = x1[k4]; a1 += xb.x*w0 + xb.y*w1 + xb.z*w2 + xb.w*w3;
                float4 xc = x2[k4]; a2 += xc.x*w0 + xc.y*w1 + xc.z*w2 + xc.w*w3;
                float4 xd = x3[k4]; a3 += xd.x*w0 + xd.y*w1 + xd.z*w2 + xd.w*w3;
            }
            // recurrent part: register weights, h broadcast from LDS
            #pragma unroll
            for (int q = 0; q < 25; ++q){
                float4 w4 = wh[q];
                float4 ha = ((const float4*)sh_h[0])[q];
                float4 hb = ((const float4*)sh_h[1])[q];
                float4 hc = ((const float4*)sh_h[2])[q];
                float4 hd = ((const float4*)sh_h[3])[q];
                a0 += ha.x*w4.x + ha.y*w4.y + ha.z*w4.z + ha.w*w4.w;
                a1 += hb.x*w4.x + hb.y*w4.y + hb.z*w4.z + hb.w*w4.w;
                a2 += hc.x*w4.x + hc.y*w4.y + hc.z*w4.z + hc.w*w4.w;
                a3 += hd.x*w4.x + hd.y*w4.y + hd.z*w4.z + hd.w*w4.w;
            }
            sh_g[n][0] = a0; sh_g[n][1] = a1; sh_g[n][2] = a2; sh_g[n][3] = a3;
        }
        __syncthreads();
        if (act){
            float ai = sh_g[jc][mc];
            float af = sh_g[NH + jc][mc];
            float ag = sh_g[2 * NH + jc][mc];
            float ao = sh_g[3 * NH + jc][mc];
            float ii = sigm(ai), ff = sigm(af), gg = tanh_fast(ag), oo = sigm(ao);
            c_reg = ff * c_reg + ii * gg;
            h_new = oo * tanh_fast(c_reg);
            sh_h[mc][jc] = h_new;
        }
        // loop-top stage + sync separates this write from next reads
    }
    if (act){
        h_out[(size_t)(m0 + mc) * NH + jc] = h_new;
        c_out[(size_t)(m0 + mc) * NH + jc] = c_reg;
    }
}

// ---------------- decoder: fully weight-stationary, 8 rows/block, 2x125 blocks ----------------

__global__ __launch_bounds__(512, 2) void decoder_kernel(
    const float* __restrict__ h_enc, const float* __restrict__ c_enc,
    const float* __restrict__ Whh_p, const float* __restrict__ Wdec_p,
    const float* __restrict__ b0_p,  const float* __restrict__ bdec_p,
    const float* __restrict__ fcW_p, const float* __restrict__ fcb_p,
    const float* __restrict__ trg,
    const float* __restrict__ Whh_r, const float* __restrict__ Wdec_r,
    const float* __restrict__ b0_r,  const float* __restrict__ bdec_r,
    const float* __restrict__ fcW_r, const float* __restrict__ fcb_r,
    const float* __restrict__ src,
    float* __restrict__ loss)
{
    __shared__ float sh_h[DM][104];
    __shared__ float sh_g[NG][DM + 1];    // stride 9: conflict-free combine reads
    __shared__ float sh_red[8];
    const int tid = threadIdx.x;
    const int d   = (blockIdx.x >= 125) ? 1 : 0;
    const int m0  = (blockIdx.x - d * 125) * DM;
    const float* Whh  = d ? Whh_r  : Whh_p;
    const float* Wdec = d ? Wdec_r : Wdec_p;
    const float* b0   = d ? b0_r   : b0_p;
    const float* bdec = d ? bdec_r : bdec_p;
    const float* fcW  = d ? fcW_r  : fcW_p;
    const float* fcb  = d ? fcb_r  : fcb_p;
    const float* tgt  = d ? src    : trg;

    const bool gate = tid < NG;
    const int n  = gate ? tid : 0;
    const bool fc = tid >= FC_BASE;
    const int o  = fc ? tid - FC_BASE : 0;
    const int mc = gate ? tid / NH : 0;   // combine pairs (mc,jc) and (mc+4,jc)
    const int jc = gate ? tid % NH : 0;

    float4 wd[25];
    float b0n = 0.f, bdn = 0.f;
    if (gate){
        const float4* p = (const float4*)(Wdec + (size_t)n * NH);
        #pragma unroll
        for (int q = 0; q < 25; ++q) wd[q] = p[q];
        b0n = b0[n]; bdn = bdec[n];
    }
    float4 wf[25];
    float fb = 0.f;
    if (fc){
        const float4* p = (const float4*)(fcW + (size_t)o * NH);
        #pragma unroll
        for (int q = 0; q < 25; ++q) wf[q] = p[q];
        fb = fcb[o];
    }
    float c0 = 0.f, c1 = 0.f;
    if (gate){
        c0 = c_enc[(size_t)(m0 + mc) * NH + jc];
        c1 = c_enc[(size_t)(m0 + 4 + mc) * NH + jc];
        sh_h[mc][jc]     = h_enc[(size_t)(m0 + mc) * NH + jc];
        sh_h[mc + 4][jc] = h_enc[(size_t)(m0 + 4 + mc) * NH + jc];
    }
    float loss_acc = 0.f;
    __syncthreads();

    for (int t = 0; t < NT; ++t){
        if (gate){
            float a[DM];
            float bb = (t == 0) ? b0n : bdn;
            #pragma unroll
            for (int m = 0; m < DM; ++m) a[m] = bb;
            if (t == 0){
                // step 0: x=0 -> plain Whh, streamed once from L2
                const float4* whp = (const float4*)(Whh + (size_t)n * NH);
                for (int q = 0; q < 25; ++q){
                    float4 w4 = whp[q];
                    #pragma unroll
                    for (int m = 0; m < DM; ++m){
                        float4 h4 = ((const float4*)sh_h[m])[q];
                        a[m] += h4.x*w4.x + h4.y*w4.y + h4.z*w4.z + h4.w*w4.w;
                    }
                }
            } else {
                #pragma unroll
                for (int q = 0; q < 25; ++q){
                    float4 w4 = wd[q];
                    #pragma unroll
                    for (int m = 0; m < DM; ++m){
                        float4 h4 = ((const float4*)sh_h[m])[q];
                        a[m] += h4.x*w4.x + h4.y*w4.y + h4.z*w4.z + h4.w*w4.w;
                    }
                }
            }
            #pragma unroll
            for (int m = 0; m < DM; ++m) sh_g[n][m] = a[m];
        }
        __syncthreads();
        if (gate){
            {   // pair (mc, jc)
                float ai = sh_g[jc][mc], af = sh_g[NH + jc][mc];
                float ag = sh_g[2 * NH + jc][mc], ao = sh_g[3 * NH + jc][mc];
                float ii = sigm(ai), ff = sigm(af), gg = tanh_fast(ag), oo = sigm(ao);
                c0 = ff * c0 + ii * gg;
                sh_h[mc][jc] = oo * tanh_fast(c0);
            }
            {   // pair (mc+4, jc)
                float ai = sh_g[jc][mc + 4], af = sh_g[NH + jc][mc + 4];
                float ag = sh_g[2 * NH + jc][mc + 4], ao = sh_g[3 * NH + jc][mc + 4];
                float ii = sigm(ai), ff = sigm(af), gg = tanh_fast(ag), oo = sigm(ao);
                c1 = ff * c1 + ii * gg;
                sh_h[mc + 4][jc] = oo * tanh_fast(c1);
            }
        }
        __syncthreads();
        if (fc){
            const int ti = d ? (NT - 1 - t) : t;
            float acc[DM];
            #pragma unroll
            for (int m = 0; m < DM; ++m) acc[m] = fb;
            #pragma unroll
            for (int q = 0; q < 25; ++q){
                float4 w4 = wf[q];
                #pragma unroll
                for (int m = 0; m < DM; ++m){
                    float4 h4 = ((const float4*)sh_h[m])[q];
                    acc[m] += h4.x*w4.x + h4.y*w4.y + h4.z*w4.z + h4.w*w4.w;
                }
            }
            const float* tg = tgt + (size_t)m0 * NT * NI + (size_t)ti * NI + o;
            #pragma unroll
            for (int m = 0; m < DM; ++m){
                float df = acc[m] - tg[(size_t)m * NT * NI];
                loss_acc += df * df;
            }
        }
        // next A / this B both only read sh_h; next A's write is after SYNC1
    }

    for (int off = 32; off > 0; off >>= 1) loss_acc += __shfl_down(loss_acc, off);
    if ((tid & 63) == 0) sh_red[tid >> 6] = loss_acc;
    __syncthreads();
    if (tid == 0){
        float s = 0.f;
        for (int w = 0; w < 8; ++w) s += sh_red[w];
        atomicAdd(&loss[d], s);
    }
}

__global__ void finalize_kernel(const float* __restrict__ loss, float* __restrict__ out){
    if (threadIdx.x == 0){
        const float inv = 1.f / 26400000.f;   // B*T*O
        out[0] = loss[1] * inv;   // reconstruct_loss
        out[1] = loss[0] * inv;   // predict_loss
    }
}

extern "C" void kernel_launch(void* const* d_in, const int* in_sizes, int n_in,
                              void* d_out, int out_size, void* d_ws, size_t ws_size,
                              hipStream_t stream)
{
    const float* src  = (const float*)d_in[0];
    const float* trg  = (const float*)d_in[1];
    const float* eWih = (const float*)d_in[2];
    const float* eWhh = (const float*)d_in[3];
    const float* ebih = (const float*)d_in[4];
    const float* ebhh = (const float*)d_in[5];
    const float* pWih = (const float*)d_in[6];
    const float* pWhh = (const float*)d_in[7];
    const float* pbih = (const float*)d_in[8];
    const float* pbhh = (const float*)d_in[9];
    const float* pfcW = (const float*)d_in[10];
    const float* pfcb = (const float*)d_in[11];
    const float* rWih = (const float*)d_in[12];
    const float* rWhh = (const float*)d_in[13];
    const float* rbih = (const float*)d_in[14];
    const float* rbhh = (const float*)d_in[15];
    const float* rfcW = (const float*)d_in[16];
    const float* rfcb = (const float*)d_in[17];

    float* w      = (float*)d_ws;           // total 387,602 floats (~1.55 MB)
    float* WihT   = w;                      // 105600
    float* Wdec_p = w + 105600;             // 40000
    float* Wdec_r = w + 145600;             // 40000
    float* b0_p   = w + 185600;             // 400
    float* bdec_p = w + 186000;             // 400
    float* b0_r   = w + 186400;             // 400
    float* bdec_r = w + 186800;             // 400
    float* bcat   = w + 187200;             // 400
    float* h_enc  = w + 187600;             // 100000
    float* c_enc  = w + 287600;             // 100000
    float* loss   = w + 387600;             // 2

    prep_enc<<<(NG * NI + 255) / 256, 256, 0, stream>>>(eWih, ebih, ebhh, WihT, bcat);
    prep_wdec<<<(NG * NH + 255) / 256, 256, 0, stream>>>(pWih, pWhh, pfcW, Wdec_p);
    prep_wdec<<<(NG * NH + 255) / 256, 256, 0, stream>>>(rWih, rWhh, rfcW, Wdec_r);
    prep_bias<<<4, 256, 0, stream>>>(pbih, pbhh, pWih, pfcb, rbih, rbhh, rWih, rfcb,
                                     b0_p, bdec_p, b0_r, bdec_r, loss);
    encoder_kernel<<<250, 512, 0, stream>>>(src, WihT, eWhh, bcat, h_enc, c_enc);
    decoder_kernel<<<250, 512, 0, stream>>>(h_enc, c_enc,
        pWhh, Wdec_p, b0_p, bdec_p, pfcW, pfcb, trg,
        rWhh, Wdec_r, b0_r, bdec_r, rfcW, rfcb, src,
        loss);
    finalize_kernel<<<1, 64, 0, stream>>>(loss, (float*)d_out);
}

// Round 3
// 4832.714 us; speedup vs baseline: 1.4481x; 1.1937x over previous
//
#include <hip/hip_runtime.h>
#include <math.h>

#define NB 1000
#define NT 100
#define NI 264
#define NH 100
#define NO 264
#define NG 400          // 4*NH
#define EM 4            // encoder rows per block (250 blocks)
#define DM 8            // decoder rows per block (125 blocks per decoder)
#define DTH 704         // decoder threads: 0-399 gate, 400-663 fc, 664-703 idle

__device__ __forceinline__ float sigm(float x){ return 1.f / (1.f + __expf(-x)); }
__device__ __forceinline__ float tanh_fast(float x){
    float e = __expf(-2.f * x);
    return 2.f / (1.f + e) - 1.f;
}

// ---------------- prep kernels ----------------

// Wih4[((k/4)*NG + n)*4 + (k&3)] = Wih[n*NI+k]  -> per-(k4,n) float4, coalesced dwordx4 loads
// bcat = bih + bhh
__global__ void prep_enc(const float* __restrict__ Wih,
                         const float* __restrict__ bih, const float* __restrict__ bhh,
                         float* __restrict__ Wih4, float* __restrict__ bcat)
{
    int idx = blockIdx.x * 256 + threadIdx.x;
    if (idx < NG * NI){
        int j  = idx & 3;
        int n  = (idx >> 2) % NG;
        int k4 = idx / (4 * NG);
        Wih4[idx] = Wih[n * NI + k4 * 4 + j];
    }
    if (idx < NG) bcat[idx] = bih[idx] + bhh[idx];
}

// Wdec[n][k] = Whh[n][k] + sum_o Wih[n][o] * fcW[o][k]   (decoder feedback folded in)
__global__ void prep_wdec(const float* __restrict__ Wih, const float* __restrict__ Whh,
                          const float* __restrict__ fcW, float* __restrict__ Wdec)
{
    int idx = blockIdx.x * 256 + threadIdx.x;
    if (idx >= NG * NH) return;
    int n = idx / NH, k = idx - n * NH;
    float acc = Whh[idx];
    const float* wr = Wih + (size_t)n * NI;
    for (int o = 0; o < NI; ++o) acc = fmaf(wr[o], fcW[o * NH + k], acc);
    Wdec[idx] = acc;
}

// b0 = bih+bhh ; bdec = b0 + Wih @ fcb ; zero the two loss accumulators
__global__ void prep_bias(const float* __restrict__ pb1, const float* __restrict__ pb2,
                          const float* __restrict__ pW,  const float* __restrict__ pfb,
                          const float* __restrict__ rb1, const float* __restrict__ rb2,
                          const float* __restrict__ rW,  const float* __restrict__ rfb,
                          float* __restrict__ b0_p, float* __restrict__ bdec_p,
                          float* __restrict__ b0_r, float* __restrict__ bdec_r,
                          float* __restrict__ loss)
{
    int tid = blockIdx.x * 256 + threadIdx.x;
    if (tid < 2) loss[tid] = 0.f;
    if (tid >= 2 * NG) return;
    int dd = tid / NG, n = tid - dd * NG;
    const float* b1 = dd ? rb1 : pb1;
    const float* b2 = dd ? rb2 : pb2;
    const float* W  = dd ? rW  : pW;
    const float* fb = dd ? rfb : pfb;
    float base = b1[n] + b2[n];
    float acc = base;
    const float* wr = W + (size_t)n * NI;
    for (int o = 0; o < NI; ++o) acc = fmaf(wr[o], fb[o], acc);
    if (dd){ b0_r[n] = base; bdec_r[n] = acc; }
    else   { b0_p[n] = base; bdec_p[n] = acc; }
}

// ---------------- encoder: weight-stationary Whh, streamed Wih4, 4 rows/block ----------------
// launch_bounds(512,1): 256-VGPR cap -> wh[25] (100 VGPR) stays register-resident, NO SPILL.

__global__ __launch_bounds__(512, 1) void encoder_kernel(
    const float* __restrict__ src, const float* __restrict__ Wih4,
    const float* __restrict__ Whh, const float* __restrict__ bcat,
    float* __restrict__ h_out, float* __restrict__ c_out)
{
    __shared__ float sh_x[2][EM][NI];     // double-buffered x_t staging
    __shared__ float sh_h[EM][104];       // h (padded row stride)
    __shared__ float sh_g[NG][EM + 1];    // gates, stride 5 (gcd(5,32)=1, conflict-free)
    const int tid = threadIdx.x;
    const int m0  = blockIdx.x * EM;
    const bool act = tid < NG;
    const int n  = act ? tid : 0;
    const int mc = n / NH;
    const int jc = n % NH;

    float4 wh[25];                        // Whh row n, register-resident
    float bias = 0.f;
    if (act){
        const float4* whp = (const float4*)(Whh + (size_t)n * NH);
        #pragma unroll
        for (int q = 0; q < 25; ++q) wh[q] = whp[q];
        bias = bcat[n];
        sh_h[mc][jc] = 0.f;               // h0 = 0
    }
    float c_reg = 0.f, h_new = 0.f;
    const float*  s0 = src + (size_t)m0 * NT * NI;
    const float4* W4 = (const float4*)Wih4;

    // preload x_0 into buffer 0
    for (int i = tid; i < EM * NI; i += 512){
        int r = i / NI, k = i - r * NI;
        sh_x[0][r][k] = s0[(size_t)r * NT * NI + k];
    }
    __syncthreads();

    for (int t = 0; t < NT; ++t){
        const int cur = t & 1;
        // stage x_{t+1} into the other buffer (overlaps with gate compute below)
        if (t + 1 < NT){
            for (int i = tid; i < EM * NI; i += 512){
                int r = i / NI, k = i - r * NI;
                sh_x[cur ^ 1][r][k] = s0[(size_t)r * NT * NI + (size_t)(t + 1) * NI + k];
            }
        }
        if (act){
            float a0 = bias, a1 = bias, a2 = bias, a3 = bias;
            const float4* x0 = (const float4*)sh_x[cur][0];
            const float4* x1 = (const float4*)sh_x[cur][1];
            const float4* x2 = (const float4*)sh_x[cur][2];
            const float4* x3 = (const float4*)sh_x[cur][3];
            // x-projection: Wih4 streamed from L2 (one dwordx4/lane), x broadcast from LDS
            #pragma unroll 4
            for (int k4 = 0; k4 < NI / 4; ++k4){
                float4 w = W4[k4 * NG + n];
                float4 xa = x0[k4]; a0 += xa.x*w.x + xa.y*w.y + xa.z*w.z + xa.w*w.w;
                float4 xb = x1[k4]; a1 += xb.x*w.x + xb.y*w.y + xb.z*w.z + xb.w*w.w;
                float4 xc = x2[k4]; a2 += xc.x*w.x + xc.y*w.y + xc.z*w.z + xc.w*w.w;
                float4 xd = x3[k4]; a3 += xd.x*w.x + xd.y*w.y + xd.z*w.z + xd.w*w.w;
            }
            // recurrent part: register weights, h broadcast from LDS
            #pragma unroll
            for (int q = 0; q < 25; ++q){
                float4 w4 = wh[q];
                float4 ha = ((const float4*)sh_h[0])[q];
                float4 hb = ((const float4*)sh_h[1])[q];
                float4 hc = ((const float4*)sh_h[2])[q];
                float4 hd = ((const float4*)sh_h[3])[q];
                a0 += ha.x*w4.x + ha.y*w4.y + ha.z*w4.z + ha.w*w4.w;
                a1 += hb.x*w4.x + hb.y*w4.y + hb.z*w4.z + hb.w*w4.w;
                a2 += hc.x*w4.x + hc.y*w4.y + hc.z*w4.z + hc.w*w4.w;
                a3 += hd.x*w4.x + hd.y*w4.y + hd.z*w4.z + hd.w*w4.w;
            }
            sh_g[n][0] = a0; sh_g[n][1] = a1; sh_g[n][2] = a2; sh_g[n][3] = a3;
        }
        __syncthreads();
        if (act){
            float ai = sh_g[jc][mc];
            float af = sh_g[NH + jc][mc];
            float ag = sh_g[2 * NH + jc][mc];
            float ao = sh_g[3 * NH + jc][mc];
            float ii = sigm(ai), ff = sigm(af), gg = tanh_fast(ag), oo = sigm(ao);
            c_reg = ff * c_reg + ii * gg;
            h_new = oo * tanh_fast(c_reg);
            sh_h[mc][jc] = h_new;
        }
        __syncthreads();
    }
    if (act){
        h_out[(size_t)(m0 + mc) * NH + jc] = h_new;
        c_out[(size_t)(m0 + mc) * NH + jc] = c_reg;
    }
}

// ---------------- decoder: disjoint gate/fc roles, overlapped pipeline ----------------
// 704 threads = 11 waves -> 3 waves/SIMD -> 170-VGPR cap; wreg[25]=100 VGPR, ~140 total.
// One wreg array overlays Wdec-row (gate threads) and fcW-row (fc threads): no double
// allocation, no spill. Pipeline: iter k runs gate-matvec(H_k -> gates_{k+1}) CONCURRENTLY
// with fc-output(H_k -> pred_{k-1} + loss) on different waves; both only read sh_h.

__global__ __launch_bounds__(DTH, 1) void decoder_kernel(
    const float* __restrict__ h_enc, const float* __restrict__ c_enc,
    const float* __restrict__ Whh_p, const float* __restrict__ Wdec_p,
    const float* __restrict__ b0_p,  const float* __restrict__ bdec_p,
    const float* __restrict__ fcW_p, const float* __restrict__ fcb_p,
    const float* __restrict__ trg,
    const float* __restrict__ Whh_r, const float* __restrict__ Wdec_r,
    const float* __restrict__ b0_r,  const float* __restrict__ bdec_r,
    const float* __restrict__ fcW_r, const float* __restrict__ fcb_r,
    const float* __restrict__ src,
    float* __restrict__ loss)
{
    __shared__ float sh_h[DM][104];
    __shared__ float sh_g[NG][DM + 1];    // stride 9: gcd(9,32)=1, conflict-free
    __shared__ float sh_red[11];
    const int tid = threadIdx.x;
    const int d   = (blockIdx.x >= 125) ? 1 : 0;
    const int m0  = (blockIdx.x - d * 125) * DM;
    const float* Whh  = d ? Whh_r  : Whh_p;
    const float* Wdec = d ? Wdec_r : Wdec_p;
    const float* b0   = d ? b0_r   : b0_p;
    const float* bdec = d ? bdec_r : bdec_p;
    const float* fcW  = d ? fcW_r  : fcW_p;
    const float* fcb  = d ? fcb_r  : fcb_p;
    const float* tgt  = d ? src    : trg;

    const bool gate = tid < NG;
    const bool fc   = (tid >= NG) && (tid < NG + NO);
    const int n  = gate ? tid : 0;
    const int o  = fc ? tid - NG : 0;
    const int mc = n / NH;
    const int jc = n % NH;

    float4 wreg[25];                      // gate: Wdec row n | fc: fcW row o (overlaid!)
    float b0n = 0.f, bdn = 0.f, fb = 0.f;
    if (gate){
        const float4* p = (const float4*)(Wdec + (size_t)n * NH);
        #pragma unroll
        for (int q = 0; q < 25; ++q) wreg[q] = p[q];
        b0n = b0[n]; bdn = bdec[n];
    } else if (fc){
        const float4* p = (const float4*)(fcW + (size_t)o * NH);
        #pragma unroll
        for (int q = 0; q < 25; ++q) wreg[q] = p[q];
        fb = fcb[o];
    }
    float c0 = 0.f, c1 = 0.f;
    if (gate){
        c0 = c_enc[(size_t)(m0 + mc) * NH + jc];
        c1 = c_enc[(size_t)(m0 + 4 + mc) * NH + jc];
        sh_h[mc][jc]     = h_enc[(size_t)(m0 + mc) * NH + jc];
        sh_h[mc + 4][jc] = h_enc[(size_t)(m0 + 4 + mc) * NH + jc];
    }
    float loss_acc = 0.f;
    __syncthreads();

    for (int k = 0; k <= NT; ++k){
        // ---- phase A: gate matvec (k<NT) runs concurrently with fc output (k>=1) ----
        if (gate && k < NT){
            float a[DM];
            float bb = k ? bdn : b0n;
            #pragma unroll
            for (int m = 0; m < DM; ++m) a[m] = bb;
            if (k == 0){
                // step 0: x=0 -> plain Whh, streamed once from L2
                const float4* whp = (const float4*)(Whh + (size_t)n * NH);
                for (int q = 0; q < 25; ++q){
                    float4 w4 = whp[q];
                    #pragma unroll
                    for (int m = 0; m < DM; ++m){
                        float4 h4 = ((const float4*)sh_h[m])[q];
                        a[m] += h4.x*w4.x + h4.y*w4.y + h4.z*w4.z + h4.w*w4.w;
                    }
                }
            } else {
                #pragma unroll
                for (int q = 0; q < 25; ++q){
                    float4 w4 = wreg[q];
                    #pragma unroll
                    for (int m = 0; m < DM; ++m){
                        float4 h4 = ((const float4*)sh_h[m])[q];
                        a[m] += h4.x*w4.x + h4.y*w4.y + h4.z*w4.z + h4.w*w4.w;
                    }
                }
            }
            #pragma unroll
            for (int m = 0; m < DM; ++m) sh_g[n][m] = a[m];
        } else if (fc && k >= 1){
            float a[DM];
            #pragma unroll
            for (int m = 0; m < DM; ++m) a[m] = fb;
            #pragma unroll
            for (int q = 0; q < 25; ++q){
                float4 w4 = wreg[q];
                #pragma unroll
                for (int m = 0; m < DM; ++m){
                    float4 h4 = ((const float4*)sh_h[m])[q];
                    a[m] += h4.x*w4.x + h4.y*w4.y + h4.z*w4.z + h4.w*w4.w;
                }
            }
            const int ti = d ? (NT - k) : (k - 1);   // pred index k-1, reversed for recon
            const float* tg = tgt + (size_t)m0 * NT * NI + (size_t)ti * NI + o;
            #pragma unroll
            for (int m = 0; m < DM; ++m){
                float df = a[m] - tg[(size_t)m * NT * NI];
                loss_acc += df * df;
            }
        }
        __syncthreads();
        // ---- phase B: nonlinearity + h update ----
        if (gate && k < NT){
            {   // pair (mc, jc)
                float ai = sh_g[jc][mc], af = sh_g[NH + jc][mc];
                float ag = sh_g[2 * NH + jc][mc], ao = sh_g[3 * NH + jc][mc];
                float ii = sigm(ai), ff = sigm(af), gg = tanh_fast(ag), oo = sigm(ao);
                c0 = ff * c0 + ii * gg;
                sh_h[mc][jc] = oo * tanh_fast(c0);
            }
            {   // pair (mc+4, jc)
                float ai = sh_g[jc][mc + 4], af = sh_g[NH + jc][mc + 4];
                float ag = sh_g[2 * NH + jc][mc + 4], ao = sh_g[3 * NH + jc][mc + 4];
                float ii = sigm(ai), ff = sigm(af), gg = tanh_fast(ag), oo = sigm(ao);
                c1 = ff * c1 + ii * gg;
                sh_h[mc + 4][jc] = oo * tanh_fast(c1);
            }
        }
        __syncthreads();
    }

    // block loss reduction -> one atomic per block
    for (int off = 32; off > 0; off >>= 1) loss_acc += __shfl_down(loss_acc, off);
    if ((tid & 63) == 0) sh_red[tid >> 6] = loss_acc;
    __syncthreads();
    if (tid == 0){
        float s = 0.f;
        for (int w = 0; w < 11; ++w) s += sh_red[w];
        atomicAdd(&loss[d], s);
    }
}

__global__ void finalize_kernel(const float* __restrict__ loss, float* __restrict__ out){
    if (threadIdx.x == 0){
        const float inv = 1.f / 26400000.f;   // B*T*O
        out[0] = loss[1] * inv;   // reconstruct_loss
        out[1] = loss[0] * inv;   // predict_loss
    }
}

extern "C" void kernel_launch(void* const* d_in, const int* in_sizes, int n_in,
                              void* d_out, int out_size, void* d_ws, size_t ws_size,
                              hipStream_t stream)
{
    const float* src  = (const float*)d_in[0];
    const float* trg  = (const float*)d_in[1];
    const float* eWih = (const float*)d_in[2];
    const float* eWhh = (const float*)d_in[3];
    const float* ebih = (const float*)d_in[4];
    const float* ebhh = (const float*)d_in[5];
    const float* pWih = (const float*)d_in[6];
    const float* pWhh = (const float*)d_in[7];
    const float* pbih = (const float*)d_in[8];
    const float* pbhh = (const float*)d_in[9];
    const float* pfcW = (const float*)d_in[10];
    const float* pfcb = (const float*)d_in[11];
    const float* rWih = (const float*)d_in[12];
    const float* rWhh = (const float*)d_in[13];
    const float* rbih = (const float*)d_in[14];
    const float* rbhh = (const float*)d_in[15];
    const float* rfcW = (const float*)d_in[16];
    const float* rfcb = (const float*)d_in[17];

    float* w      = (float*)d_ws;           // total 387,602 floats (~1.55 MB)
    float* Wih4   = w;                      // 105600
    float* Wdec_p = w + 105600;             // 40000
    float* Wdec_r = w + 145600;             // 40000
    float* b0_p   = w + 185600;             // 400
    float* bdec_p = w + 186000;             // 400
    float* b0_r   = w + 186400;             // 400
    float* bdec_r = w + 186800;             // 400
    float* bcat   = w + 187200;             // 400
    float* h_enc  = w + 187600;             // 100000
    float* c_enc  = w + 287600;             // 100000
    float* loss   = w + 387600;             // 2

    prep_enc<<<(NG * NI + 255) / 256, 256, 0, stream>>>(eWih, ebih, ebhh, Wih4, bcat);
    prep_wdec<<<(NG * NH + 255) / 256, 256, 0, stream>>>(pWih, pWhh, pfcW, Wdec_p);
    prep_wdec<<<(NG * NH + 255) / 256, 256, 0, stream>>>(rWih, rWhh, rfcW, Wdec_r);
    prep_bias<<<4, 256, 0, stream>>>(pbih, pbhh, pWih, pfcb, rbih, rbhh, rWih, rfcb,
                                     b0_p, bdec_p, b0_r, bdec_r, loss);
    encoder_kernel<<<250, 512, 0, stream>>>(src, Wih4, eWhh, bcat, h_enc, c_enc);
    decoder_kernel<<<250, DTH, 0, stream>>>(h_enc, c_enc,
        pWhh, Wdec_p, b0_p, bdec_p, pfcW, pfcb, trg,
        rWhh, Wdec_r, b0_r, bdec_r, rfcW, rfcb, src,
        loss);
    finalize_kernel<<<1, 64, 0, stream>>>(loss, (float*)d_out);
}